// Round 10
// baseline (227.115 us; speedup 1.0000x reference)
//
#include <hip/hip_runtime.h>
#include <stdint.h>

typedef __attribute__((ext_vector_type(8))) short bf16x8;
typedef __attribute__((ext_vector_type(4))) float f32x4;

// ---------------- workspace layout (bytes) ----------------
#define WS_WQKV   0u               // 384*256 bf16 = 196608
#define WS_WZ     196608u          // 256*128 bf16 = 65536
#define WS_SCL    262144u          // 384 f32 (QKV fused BN scale)
#define WS_SHF    263680u          // 384 f32 (QKV fused BN shift)
#define WS_WZS    265216u          // 256 f32 (out BN scale)
#define WS_WZT    266240u          // 256 f32 (out BN shift)
#define WS_Q      524288u          // [4][4096][128] bf16 = 4 MB (pre-scaled by s2)
#define WS_K      (WS_Q  + 4194304u)
#define WS_VT     (WS_K  + 4194304u)   // [4][128][4096] bf16 (transposed V)
#define WS_Y      (WS_VT + 4194304u)   // (spare)
#define WS_OP     (WS_Y  + 4194304u)   // [4 mc][4 b][4096][128] bf16 partials = 16 MB
#define WS_LP     (WS_OP + 16777216u)  // [4 mc][4 b][4096] f32 partial denoms = 256 KB

__device__ __forceinline__ short f2bf(float f) {
  union { float f; uint32_t u; } v; v.f = f;
  uint32_t r = v.u + 0x7fffu + ((v.u >> 16) & 1u);
  return (short)(r >> 16);
}

// round-half-up pair pack: 2 floats -> 2 bf16 in one u32 (cheap, <=1ulp bias)
__device__ __forceinline__ uint32_t pack2_bf16(float a, float b) {
  union { float f; uint32_t u; } x, y; x.f = a; y.f = b;
  return ((y.u + 0x8000u) & 0xffff0000u) | ((x.u + 0x8000u) >> 16);
}

__device__ __forceinline__ f32x4 mfma16(bf16x8 a, bf16x8 b, f32x4 c) {
  return __builtin_amdgcn_mfma_f32_16x16x32_bf16(a, b, c, 0, 0, 0);
}

// ---------------- kernel 0: weight prep + BN folding ----------------
__global__ __launch_bounds__(256) void prep_kernel(
    const float* theta_w, const float* phi_w, const float* g_w, const float* wz_w,
    const float* theta_b, const float* tg, const float* tb, const float* tm, const float* tv,
    const float* phi_b,   const float* pg, const float* pb, const float* pm, const float* pv,
    const float* g_b,
    const float* wz_b, const float* bg, const float* bb, const float* bm, const float* bv,
    char* ws) {
  int idx = blockIdx.x * 256 + threadIdx.x;
  short* wqkv = (short*)(ws + WS_WQKV);
  if (idx < 98304) {
    float w;
    if (idx < 32768) w = theta_w[idx];
    else if (idx < 65536) w = phi_w[idx - 32768];
    else w = g_w[idx - 65536];
    wqkv[idx] = f2bf(w);
  }
  if (idx < 32768) ((short*)(ws + WS_WZ))[idx] = f2bf(wz_w[idx]);
  if (idx < 384) {
    float s, t;
    if (idx < 128)      { s = tg[idx] * rsqrtf(tv[idx] + 1e-5f);
                          t = (theta_b[idx] - tm[idx]) * s + tb[idx]; }
    else if (idx < 256) { int d = idx - 128; s = pg[d] * rsqrtf(pv[d] + 1e-5f);
                          t = (phi_b[d] - pm[d]) * s + pb[d]; }
    else                { int d = idx - 256; s = 1.0f; t = g_b[d]; }
    ((float*)(ws + WS_SCL))[idx] = s;
    ((float*)(ws + WS_SHF))[idx] = t;
  }
  if (idx < 256) {
    float s = bg[idx] * rsqrtf(bv[idx] + 1e-5f);
    float t = (wz_b[idx] - bm[idx]) * s + bb[idx];
    ((float*)(ws + WS_WZS))[idx] = s;
    ((float*)(ws + WS_WZT))[idx] = t;
  }
}

// ---------------- kernel 1: fused Q/K/V projection (+BN fold) ----------------
// grid (128 nt2 of 32 rows, 4 b); block 256 = 4 waves.
// Q outputs are pre-scaled by s2 = scale*log2(e) (Q feeds attention only).
__global__ __launch_bounds__(256) void qkv_kernel(const float* __restrict__ x, char* ws) {
  const int nt2 = blockIdx.x, b = blockIdx.y;
  const int t = threadIdx.x;
  __shared__ __attribute__((aligned(16))) short xs[32][264];
  const short* wqkv = (const short*)(ws + WS_WQKV);
  const float* scl = (const float*)(ws + WS_SCL);
  const float* shf = (const float*)(ws + WS_SHF);
  const int n0 = nt2 * 32;
  #pragma unroll
  for (int i = 0; i < 8; ++i) {
    int chunk = i * 256 + t;
    int c = chunk >> 3, n4 = chunk & 7;
    const float4 v = *(const float4*)(x + ((size_t)(b * 256 + c) << 12) + n0 + n4 * 4);
    xs[n4 * 4 + 0][c] = f2bf(v.x);
    xs[n4 * 4 + 1][c] = f2bf(v.y);
    xs[n4 * 4 + 2][c] = f2bf(v.z);
    xs[n4 * 4 + 3][c] = f2bf(v.w);
  }
  __syncthreads();
  const int wv = t >> 6, l = t & 63, lr = l & 15, q = l >> 4;
  const int wn = wv & 1, dh = wv >> 1;
  bf16x8 a[8];
  #pragma unroll
  for (int kt = 0; kt < 8; ++kt) a[kt] = *(const bf16x8*)&xs[wn * 16 + lr][kt * 32 + q * 8];
  f32x4 acc[12] = {};
  #pragma unroll
  for (int kt = 0; kt < 8; ++kt) {
    #pragma unroll
    for (int s = 0; s < 12; ++s) {
      const short* wp = wqkv + (size_t)(dh * 192 + s * 16 + lr) * 256 + kt * 32 + q * 8;
      bf16x8 bf = *(const bf16x8*)wp;
      acc[s] = mfma16(a[kt], bf, acc[s]);
    }
  }
  const float s2 = 0.08838834764831845f * 1.4426950408889634f;
  #pragma unroll
  for (int s = 0; s < 12; ++s) {
    int dg = dh * 192 + s * 16 + lr;
    float sc = scl[dg], sh = shf[dg];
    if (dg < 128) { sc *= s2; sh *= s2; }   // fold softmax scale into Q
    short vals[4];
    #pragma unroll
    for (int r = 0; r < 4; ++r) vals[r] = f2bf(acc[s][r] * sc + sh);
    int nbase = n0 + wn * 16 + q * 4;
    if (dg < 128) {
      short* Q = (short*)(ws + WS_Q) + ((size_t)b << 19);
      #pragma unroll
      for (int r = 0; r < 4; ++r) Q[(size_t)(nbase + r) * 128 + dg] = vals[r];
    } else if (dg < 256) {
      short* K = (short*)(ws + WS_K) + ((size_t)b << 19);
      int d = dg - 128;
      #pragma unroll
      for (int r = 0; r < 4; ++r) K[(size_t)(nbase + r) * 128 + d] = vals[r];
    } else {
      short* VT = (short*)(ws + WS_VT) + ((size_t)b << 19);
      int d = dg - 256;
      short4 pk; pk.x = vals[0]; pk.y = vals[1]; pk.z = vals[2]; pk.w = vals[3];
      *(short4*)(VT + ((size_t)d << 12) + nbase) = pk;
    }
  }
}

// ---------------- kernel 2: flash attention, fragment-order LDS layout ----------
// grid 512 (XCD-swizzled); block 256 = 4 waves sharing staged 64-m K/V tiles.
// Wave owns 32 Q-rows (2 strips); S^T = K*Q^T, O^T = V^T*P^T.
// K/V/P are stored in LDS in exact MFMA-fragment order [frag_group][lane*8]:
// every fragment read is base+lane*16B (canonical conflict-free contiguous),
// and the staging thread->chunk remap makes staging WRITES lane-linear too.
// P scatter-write lands at 2 lanes/bank (free). LDS 48KB.
// __launch_bounds__(256,2): (256,3) clamps regalloc to 84 VGPR -> spills (R8).
__global__ __launch_bounds__(256, 2) void attn_kernel(char* ws) {
  const int g = blockIdx.x;
  const int b = (g & 7) >> 1;
  const int idx = ((g >> 3) << 1) | (g & 1);     // 0..127
  const int nt = idx >> 2, mc = idx & 3;
  const int t = threadIdx.x, w = t >> 6, l = t & 63, lr = l & 15, q = l >> 4;
  // fragment-order LDS: [group][lane*8]
  __shared__ __attribute__((aligned(16))) short ksl[16][512];      // (s*4+kt)
  __shared__ __attribute__((aligned(16))) short vsl[16][512];      // (dt*2+h)
  __shared__ __attribute__((aligned(16))) short psl[4][2][2][512]; // [w][strip][h]
  const short* Q  = (const short*)(ws + WS_Q)  + ((size_t)b << 19);
  const short* K  = (const short*)(ws + WS_K)  + ((size_t)b << 19);
  const short* VT = (const short*)(ws + WS_VT) + ((size_t)b << 19);
  const int n0w = nt * 128 + w * 32;
  // Q fragments resident as B-operands (pre-scaled by s2 in qkv)
  bf16x8 qf[2][4];
  #pragma unroll
  for (int j = 0; j < 2; ++j) {
    const short* qp = Q + (size_t)(n0w + j * 16 + lr) * 128 + q * 8;
    #pragma unroll
    for (int kt = 0; kt < 4; ++kt) qf[j][kt] = *(const bf16x8*)(qp + kt * 32);
  }
  f32x4 o[2][8] = {};
  float lsum[2] = {0.f, 0.f};
  const int mbase = mc << 10;

  for (int it = 0; it < 16; ++it) {
    const int m0 = mbase + it * 64;
    __syncthreads();
    // staging with fragment-order thread remap:
    //  K chunk for group (s=i, kt=w): lane (q,lr) <- K[m0+i*16+lr][w*32+q*8]
    //  V chunk for group (dt=i*2+(w>>1), h=w&1): lane <- VT[dt*16+lr][m0+h*32+q*8]
    uint4 kr[4], vr[4];
    #pragma unroll
    for (int i = 0; i < 4; ++i) {
      kr[i] = *(const uint4*)(K + (size_t)(m0 + i * 16 + lr) * 128 + w * 32 + q * 8);
      vr[i] = *(const uint4*)(VT + ((size_t)(i * 32 + (w >> 1) * 16 + lr) << 12)
                              + m0 + (w & 1) * 32 + q * 8);
    }
    #pragma unroll
    for (int i = 0; i < 4; ++i) {
      *(uint4*)&ksl[i * 4 + w][l * 8] = kr[i];
      *(uint4*)&vsl[i * 4 + w][l * 8] = vr[i];
    }
    __syncthreads();
    // S^T = K * Q^T : A = kf (row m, k c), B = qf (col n, k c)
    f32x4 sacc[2][4] = {};
    #pragma unroll
    for (int kt = 0; kt < 4; ++kt) {
      #pragma unroll
      for (int s = 0; s < 4; ++s) {
        bf16x8 kf = *(const bf16x8*)&ksl[s * 4 + kt][l * 8];
        sacc[0][s] = mfma16(kf, qf[0][kt], sacc[0][s]);
        sacc[1][s] = mfma16(kf, qf[1][kt], sacc[1][s]);
      }
    }
    // softmax (no max subtraction, s2 pre-folded); P written in pf-fragment order:
    // value (m = s*16+q*4+r, n=lr) -> psl[w][j][s>>1][(((s&1)*2+(q>>1))*16+lr)*8+(q&1)*4+r]
    #pragma unroll
    for (int j = 0; j < 2; ++j) {
      #pragma unroll
      for (int s = 0; s < 4; ++s) {
        float e0 = exp2f(sacc[j][s][0]);
        float e1 = exp2f(sacc[j][s][1]);
        float e2 = exp2f(sacc[j][s][2]);
        float e3 = exp2f(sacc[j][s][3]);
        lsum[j] += (e0 + e1) + (e2 + e3);
        uint2 pk;
        pk.x = pack2_bf16(e0, e1);
        pk.y = pack2_bf16(e2, e3);
        *(uint2*)&psl[w][j][s >> 1][(((s & 1) * 2 + (q >> 1)) * 16 + lr) * 8 + (q & 1) * 4] = pk;
      }
    }
    // P^T fragments: lane-linear conflict-free reads
    bf16x8 pf[2][2];
    #pragma unroll
    for (int j = 0; j < 2; ++j)
      #pragma unroll
      for (int h = 0; h < 2; ++h)
        pf[j][h] = *(const bf16x8*)&psl[w][j][h][l * 8];
    // O^T += V^T * P^T
    #pragma unroll
    for (int dt = 0; dt < 8; ++dt) {
      #pragma unroll
      for (int h = 0; h < 2; ++h) {
        bf16x8 vf = *(const bf16x8*)&vsl[dt * 2 + h][l * 8];
        o[0][dt] = mfma16(vf, pf[0][h], o[0][dt]);
        o[1][dt] = mfma16(vf, pf[1][h], o[1][dt]);
      }
    }
  }
  // epilogue: write unnormalized partials
  const int cb = mc * 4 + b;
  float* LP = (float*)(ws + WS_LP) + ((size_t)cb << 12);
  #pragma unroll
  for (int j = 0; j < 2; ++j) {
    float s = lsum[j];
    s += __shfl_xor(s, 16, 64);
    s += __shfl_xor(s, 32, 64);
    if (l < 16) LP[n0w + j * 16 + l] = s;
  }
  short* OPc = (short*)(ws + WS_OP) + ((size_t)cb << 19);
  #pragma unroll
  for (int j = 0; j < 2; ++j)
    #pragma unroll
    for (int dt = 0; dt < 8; ++dt) {
      short4 pk;
      pk.x = f2bf(o[j][dt][0]); pk.y = f2bf(o[j][dt][1]);
      pk.z = f2bf(o[j][dt][2]); pk.w = f2bf(o[j][dt][3]);
      *(short4*)&OPc[((size_t)(n0w + j * 16 + lr) << 7) + dt * 16 + q * 4] = pk;
    }
}

// ---------------- kernel 3: merge partials + W_z projection + BN2d + residual ----
// grid (256 nt of 16 rows, 4 b); block 256 = 4 waves (wave = c-quarter).
__global__ __launch_bounds__(256) void proj_kernel(const float* __restrict__ x,
                                                   char* ws, float* __restrict__ out) {
  const int nt = blockIdx.x, b = blockIdx.y;
  const int t = threadIdx.x, wv = t >> 6, l = t & 63, lr = l & 15, q = l >> 4;
  __shared__ __attribute__((aligned(16))) short ys[16][136];
  const short* OP = (const short*)(ws + WS_OP);
  const float* LP = (const float*)(ws + WS_LP);
  const short* WZ = (const short*)(ws + WS_WZ);
  const float* wzs = (const float*)(ws + WS_WZS);
  const float* wzt = (const float*)(ws + WS_WZT);
  const int n0 = nt * 16;
  {
    int row = t >> 4, d8 = (t & 15) * 8;
    int n = n0 + row;
    float acc8[8] = {};
    float lsf = 0.f;
    #pragma unroll
    for (int mc = 0; mc < 4; ++mc) {
      int cb = mc * 4 + b;
      const short* p = OP + ((size_t)cb << 19) + ((size_t)n << 7) + d8;
      uint4 v = *(const uint4*)p;
      uint32_t uu[4] = {v.x, v.y, v.z, v.w};
      #pragma unroll
      for (int w = 0; w < 4; ++w) {
        union { uint32_t u; float f; } lo, hi;
        lo.u = uu[w] << 16; hi.u = uu[w] & 0xffff0000u;
        acc8[w * 2 + 0] += lo.f;
        acc8[w * 2 + 1] += hi.f;
      }
      lsf += LP[(cb << 12) + n];
    }
    float inv = 1.0f / lsf;
    short out8[8];
    #pragma unroll
    for (int j = 0; j < 8; ++j) out8[j] = f2bf(acc8[j] * inv);
    *(uint4*)&ys[row][d8] = *(uint4*)out8;
  }
  __syncthreads();
  bf16x8 a[4];
  #pragma unroll
  for (int kt = 0; kt < 4; ++kt) a[kt] = *(const bf16x8*)&ys[lr][kt * 32 + q * 8];
  f32x4 acc[4] = {};
  #pragma unroll
  for (int kt = 0; kt < 4; ++kt) {
    #pragma unroll
    for (int s = 0; s < 4; ++s) {
      const short* wp = WZ + (size_t)(wv * 64 + s * 16 + lr) * 128 + kt * 32 + q * 8;
      bf16x8 bf = *(const bf16x8*)wp;
      acc[s] = mfma16(a[kt], bf, acc[s]);
    }
  }
  #pragma unroll
  for (int s = 0; s < 4; ++s) {
    int c = wv * 64 + s * 16 + lr;
    float sc = wzs[c], sh = wzt[c];
    int nbase = n0 + q * 4;
    size_t base = ((size_t)(b * 256 + c) << 12) + nbase;
    float4 xv = *(const float4*)(x + base);
    float4 ov;
    ov.x = acc[s][0] * sc + sh + xv.x;
    ov.y = acc[s][1] * sc + sh + xv.y;
    ov.z = acc[s][2] * sc + sh + xv.z;
    ov.w = acc[s][3] * sc + sh + xv.w;
    *(float4*)(out + base) = ov;
  }
}

// ---------------- launcher ----------------
extern "C" void kernel_launch(void* const* d_in, const int* in_sizes, int n_in,
                              void* d_out, int out_size, void* d_ws, size_t ws_size,
                              hipStream_t stream) {
  const float* x       = (const float*)d_in[0];
  const float* theta_w = (const float*)d_in[1];
  const float* theta_b = (const float*)d_in[2];
  const float* tg      = (const float*)d_in[3];
  const float* tb      = (const float*)d_in[4];
  const float* tm      = (const float*)d_in[5];
  const float* tv      = (const float*)d_in[6];
  const float* phi_w   = (const float*)d_in[7];
  const float* phi_b   = (const float*)d_in[8];
  const float* pg      = (const float*)d_in[9];
  const float* pb      = (const float*)d_in[10];
  const float* pm      = (const float*)d_in[11];
  const float* pv      = (const float*)d_in[12];
  const float* g_w     = (const float*)d_in[13];
  const float* g_b     = (const float*)d_in[14];
  const float* wz_w    = (const float*)d_in[15];
  const float* wz_b    = (const float*)d_in[16];
  const float* bg      = (const float*)d_in[17];
  const float* bb      = (const float*)d_in[18];
  const float* bm      = (const float*)d_in[19];
  const float* bv      = (const float*)d_in[20];
  char* ws = (char*)d_ws;
  float* out = (float*)d_out;

  prep_kernel<<<384, 256, 0, stream>>>(theta_w, phi_w, g_w, wz_w,
                                       theta_b, tg, tb, tm, tv,
                                       phi_b, pg, pb, pm, pv,
                                       g_b, wz_b, bg, bb, bm, bv, ws);
  qkv_kernel<<<dim3(128, 4), 256, 0, stream>>>(x, ws);
  attn_kernel<<<512, 256, 0, stream>>>(ws);
  proj_kernel<<<dim3(256, 4), 256, 0, stream>>>(x, ws, out);
}

// Round 11
// 196.933 us; speedup vs baseline: 1.1533x; 1.1533x over previous
//
#include <hip/hip_runtime.h>
#include <stdint.h>

typedef __attribute__((ext_vector_type(8))) short bf16x8;
typedef __attribute__((ext_vector_type(4))) float f32x4;

// ---------------- workspace layout (bytes) ----------------
#define WS_WQKV   0u               // 384*256 bf16 = 196608
#define WS_WZ     196608u          // 256*128 bf16 = 65536
#define WS_SCL    262144u          // 384 f32 (QKV fused BN scale)
#define WS_SHF    263680u          // 384 f32 (QKV fused BN shift)
#define WS_WZS    265216u          // 256 f32 (out BN scale)
#define WS_WZT    266240u          // 256 f32 (out BN shift)
#define WS_Q      524288u          // [4][4096][128] bf16 row-major (pre-scaled by s2)
#define WS_K      (WS_Q  + 4194304u)   // [4][64 tile][16 grp][64 lane][8] bf16 frag-tiled
#define WS_VT     (WS_K  + 4194304u)   // [4][64 tile][16 grp][64 lane][8] bf16 frag-tiled
#define WS_Y      (WS_VT + 4194304u)   // (spare)
#define WS_OP     (WS_Y  + 4194304u)   // [4 mc][4 b][4096][128] bf16 partials = 16 MB
#define WS_LP     (WS_OP + 16777216u)  // [4 mc][4 b][4096] f32 partial denoms = 256 KB

__device__ __forceinline__ short f2bf(float f) {
  union { float f; uint32_t u; } v; v.f = f;
  uint32_t r = v.u + 0x7fffu + ((v.u >> 16) & 1u);
  return (short)(r >> 16);
}

// round-half-up pair pack: 2 floats -> 2 bf16 in one u32 (cheap, <=1ulp bias)
__device__ __forceinline__ uint32_t pack2_bf16(float a, float b) {
  union { float f; uint32_t u; } x, y; x.f = a; y.f = b;
  return ((y.u + 0x8000u) & 0xffff0000u) | ((x.u + 0x8000u) >> 16);
}

__device__ __forceinline__ f32x4 mfma16(bf16x8 a, bf16x8 b, f32x4 c) {
  return __builtin_amdgcn_mfma_f32_16x16x32_bf16(a, b, c, 0, 0, 0);
}

// async global->LDS DMA, 16B/lane: dest = wave-uniform base + lane*16
__device__ __forceinline__ void load_lds16(const short* gp, short* lp) {
  __builtin_amdgcn_global_load_lds(
      (const __attribute__((address_space(1))) uint32_t*)gp,
      (__attribute__((address_space(3))) uint32_t*)lp, 16, 0, 0);
}

// ---------------- kernel 0: weight prep + BN folding ----------------
__global__ __launch_bounds__(256) void prep_kernel(
    const float* theta_w, const float* phi_w, const float* g_w, const float* wz_w,
    const float* theta_b, const float* tg, const float* tb, const float* tm, const float* tv,
    const float* phi_b,   const float* pg, const float* pb, const float* pm, const float* pv,
    const float* g_b,
    const float* wz_b, const float* bg, const float* bb, const float* bm, const float* bv,
    char* ws) {
  int idx = blockIdx.x * 256 + threadIdx.x;
  short* wqkv = (short*)(ws + WS_WQKV);
  if (idx < 98304) {
    float w;
    if (idx < 32768) w = theta_w[idx];
    else if (idx < 65536) w = phi_w[idx - 32768];
    else w = g_w[idx - 65536];
    wqkv[idx] = f2bf(w);
  }
  if (idx < 32768) ((short*)(ws + WS_WZ))[idx] = f2bf(wz_w[idx]);
  if (idx < 384) {
    float s, t;
    if (idx < 128)      { s = tg[idx] * rsqrtf(tv[idx] + 1e-5f);
                          t = (theta_b[idx] - tm[idx]) * s + tb[idx]; }
    else if (idx < 256) { int d = idx - 128; s = pg[d] * rsqrtf(pv[d] + 1e-5f);
                          t = (phi_b[d] - pm[d]) * s + pb[d]; }
    else                { int d = idx - 256; s = 1.0f; t = g_b[d]; }
    ((float*)(ws + WS_SCL))[idx] = s;
    ((float*)(ws + WS_SHF))[idx] = t;
  }
  if (idx < 256) {
    float s = bg[idx] * rsqrtf(bv[idx] + 1e-5f);
    float t = (wz_b[idx] - bm[idx]) * s + bb[idx];
    ((float*)(ws + WS_WZS))[idx] = s;
    ((float*)(ws + WS_WZT))[idx] = t;
  }
}

// ---------------- kernel 1: fused Q/K/V projection (+BN fold) ----------------
// grid (128 nt2 of 32 rows, 4 b); block 256 = 4 waves.
// Q pre-scaled by s2. K and V are written in MFMA-FRAGMENT-TILED layout:
//   tile = m>>6 (16KB/tile); K group = s*4+kt (s=(m&63)>>4, kt=c>>5),
//   lane = qa*16+lra (qa=(c>>3)&3, lra=m&15), elem = c&7.
//   V group = dt*2+h (dt=d>>4, h=(m&63)>>5), lane = qv*16+lrv
//   (qv=((m&63)>>3)&3, lrv=d&15), elem = m&7.
// This makes attn staging a pure contiguous memcpy via global_load_lds.
__global__ __launch_bounds__(256) void qkv_kernel(const float* __restrict__ x, char* ws) {
  const int nt2 = blockIdx.x, b = blockIdx.y;
  const int t = threadIdx.x;
  __shared__ __attribute__((aligned(16))) short xs[32][264];
  const short* wqkv = (const short*)(ws + WS_WQKV);
  const float* scl = (const float*)(ws + WS_SCL);
  const float* shf = (const float*)(ws + WS_SHF);
  const int n0 = nt2 * 32;
  #pragma unroll
  for (int i = 0; i < 8; ++i) {
    int chunk = i * 256 + t;
    int c = chunk >> 3, n4 = chunk & 7;
    const float4 v = *(const float4*)(x + ((size_t)(b * 256 + c) << 12) + n0 + n4 * 4);
    xs[n4 * 4 + 0][c] = f2bf(v.x);
    xs[n4 * 4 + 1][c] = f2bf(v.y);
    xs[n4 * 4 + 2][c] = f2bf(v.z);
    xs[n4 * 4 + 3][c] = f2bf(v.w);
  }
  __syncthreads();
  const int wv = t >> 6, l = t & 63, lr = l & 15, q = l >> 4;
  const int wn = wv & 1, dh = wv >> 1;
  bf16x8 a[8];
  #pragma unroll
  for (int kt = 0; kt < 8; ++kt) a[kt] = *(const bf16x8*)&xs[wn * 16 + lr][kt * 32 + q * 8];
  f32x4 acc[12] = {};
  #pragma unroll
  for (int kt = 0; kt < 8; ++kt) {
    #pragma unroll
    for (int s = 0; s < 12; ++s) {
      const short* wp = wqkv + (size_t)(dh * 192 + s * 16 + lr) * 256 + kt * 32 + q * 8;
      bf16x8 bf = *(const bf16x8*)wp;
      acc[s] = mfma16(a[kt], bf, acc[s]);
    }
  }
  const float s2 = 0.08838834764831845f * 1.4426950408889634f;
  #pragma unroll
  for (int s = 0; s < 12; ++s) {
    int dg = dh * 192 + s * 16 + lr;
    float sc = scl[dg], sh = shf[dg];
    if (dg < 128) { sc *= s2; sh *= s2; }   // fold softmax scale into Q
    short vals[4];
    #pragma unroll
    for (int r = 0; r < 4; ++r) vals[r] = f2bf(acc[s][r] * sc + sh);
    int nbase = n0 + wn * 16 + q * 4;       // 4 consecutive m, no 16-crossing
    if (dg < 128) {
      short* Q = (short*)(ws + WS_Q) + ((size_t)b << 19);
      #pragma unroll
      for (int r = 0; r < 4; ++r) Q[(size_t)(nbase + r) * 128 + dg] = vals[r];
    } else if (dg < 256) {
      int d = dg - 128;
      short* Kt = (short*)(ws + WS_K) + ((size_t)b << 19);
      int kt2 = d >> 5, qa = (d >> 3) & 3, e = d & 7;
      int tile = nbase >> 6, sg = (nbase >> 4) & 3, lr0 = nbase & 15;
      size_t base = ((size_t)((tile * 16 + sg * 4 + kt2) * 64 + qa * 16 + lr0) << 3) + e;
      #pragma unroll
      for (int r = 0; r < 4; ++r) Kt[base + r * 8] = vals[r];
    } else {
      int d = dg - 256;
      short* Vt = (short*)(ws + WS_VT) + ((size_t)b << 19);
      int dt = d >> 4, lrv = d & 15;
      int tile = nbase >> 6, mm = nbase & 63;
      int h = mm >> 5, qv = (mm >> 3) & 3, e0 = mm & 7;  // e0 in {0,4}
      size_t base = ((size_t)((tile * 16 + dt * 2 + h) * 64 + qv * 16 + lrv) << 3) + e0;
      short4 pk; pk.x = vals[0]; pk.y = vals[1]; pk.z = vals[2]; pk.w = vals[3];
      *(short4*)(Vt + base) = pk;
    }
  }
}

// ---------------- kernel 2: flash attention, frag-tiled DMA staging -------------
// grid 512 (XCD-swizzled); block 256 = 4 waves. Wave owns 32 Q-rows (2 strips);
// S^T = K*Q^T, O^T = V^T*P^T. K/V arrive pre-tiled in fragment order, so staging
// is 8 global_load_lds DMAs per wave (1KB each): contiguous global, lane-linear
// LDS, zero staging VGPRs (R10's round-trip serialization eliminated). All
// fragment reads are base+lane*16B conflict-free. LDS 48KB -> 3 blocks/CU.
// __launch_bounds__(256,2): (256,3) clamps regalloc to 84 VGPR -> spills (R8).
__global__ __launch_bounds__(256, 2) void attn_kernel(char* ws) {
  const int g = blockIdx.x;
  const int b = (g & 7) >> 1;
  const int idx = ((g >> 3) << 1) | (g & 1);     // 0..127
  const int nt = idx >> 2, mc = idx & 3;
  const int t = threadIdx.x, w = t >> 6, l = t & 63, lr = l & 15, q = l >> 4;
  __shared__ __attribute__((aligned(16))) short ksl[16][512];      // grp s*4+kt
  __shared__ __attribute__((aligned(16))) short vsl[16][512];      // grp dt*2+h
  __shared__ __attribute__((aligned(16))) short psl[4][2][2][512]; // [w][strip][h]
  const short* Q  = (const short*)(ws + WS_Q)  + ((size_t)b << 19);
  const short* Kt = (const short*)(ws + WS_K)  + ((size_t)b << 19);
  const short* Vt = (const short*)(ws + WS_VT) + ((size_t)b << 19);
  const int n0w = nt * 128 + w * 32;
  // Q fragments resident as B-operands (pre-scaled by s2 in qkv)
  bf16x8 qf[2][4];
  #pragma unroll
  for (int j = 0; j < 2; ++j) {
    const short* qp = Q + (size_t)(n0w + j * 16 + lr) * 128 + q * 8;
    #pragma unroll
    for (int kt = 0; kt < 4; ++kt) qf[j][kt] = *(const bf16x8*)(qp + kt * 32);
  }
  f32x4 o[2][8] = {};
  float lsum[2] = {0.f, 0.f};

  for (int it = 0; it < 16; ++it) {
    const int tile = mc * 16 + it;
    const short* kg = Kt + (size_t)tile * 8192;
    const short* vg = Vt + (size_t)tile * 8192;
    __syncthreads();  // previous tile fully consumed
    #pragma unroll
    for (int i = 0; i < 4; ++i) {
      int gi = i * 4 + w;
      load_lds16(kg + gi * 512 + l * 8, &ksl[gi][0]);
      load_lds16(vg + gi * 512 + l * 8, &vsl[gi][0]);
    }
    __syncthreads();  // vmcnt(0) drained here by compiler
    // S^T = K * Q^T : A = kf (row m, k c), B = qf (col n, k c)
    f32x4 sacc[2][4] = {};
    #pragma unroll
    for (int kt = 0; kt < 4; ++kt) {
      #pragma unroll
      for (int s = 0; s < 4; ++s) {
        bf16x8 kf = *(const bf16x8*)&ksl[s * 4 + kt][l * 8];
        sacc[0][s] = mfma16(kf, qf[0][kt], sacc[0][s]);
        sacc[1][s] = mfma16(kf, qf[1][kt], sacc[1][s]);
      }
    }
    // softmax (no max subtraction, s2 pre-folded); P written in pf-fragment order
    #pragma unroll
    for (int j = 0; j < 2; ++j) {
      #pragma unroll
      for (int s = 0; s < 4; ++s) {
        float e0 = exp2f(sacc[j][s][0]);
        float e1 = exp2f(sacc[j][s][1]);
        float e2 = exp2f(sacc[j][s][2]);
        float e3 = exp2f(sacc[j][s][3]);
        lsum[j] += (e0 + e1) + (e2 + e3);
        uint2 pk;
        pk.x = pack2_bf16(e0, e1);
        pk.y = pack2_bf16(e2, e3);
        *(uint2*)&psl[w][j][s >> 1][(((s & 1) * 2 + (q >> 1)) * 16 + lr) * 8 + (q & 1) * 4] = pk;
      }
    }
    // P^T fragments: lane-linear conflict-free reads
    bf16x8 pf[2][2];
    #pragma unroll
    for (int j = 0; j < 2; ++j)
      #pragma unroll
      for (int h = 0; h < 2; ++h)
        pf[j][h] = *(const bf16x8*)&psl[w][j][h][l * 8];
    // O^T += V^T * P^T
    #pragma unroll
    for (int dt = 0; dt < 8; ++dt) {
      #pragma unroll
      for (int h = 0; h < 2; ++h) {
        bf16x8 vf = *(const bf16x8*)&vsl[dt * 2 + h][l * 8];
        o[0][dt] = mfma16(vf, pf[0][h], o[0][dt]);
        o[1][dt] = mfma16(vf, pf[1][h], o[1][dt]);
      }
    }
  }
  // epilogue: write unnormalized partials
  const int cb = mc * 4 + b;
  float* LP = (float*)(ws + WS_LP) + ((size_t)cb << 12);
  #pragma unroll
  for (int j = 0; j < 2; ++j) {
    float s = lsum[j];
    s += __shfl_xor(s, 16, 64);
    s += __shfl_xor(s, 32, 64);
    if (l < 16) LP[n0w + j * 16 + l] = s;
  }
  short* OPc = (short*)(ws + WS_OP) + ((size_t)cb << 19);
  #pragma unroll
  for (int j = 0; j < 2; ++j)
    #pragma unroll
    for (int dt = 0; dt < 8; ++dt) {
      short4 pk;
      pk.x = f2bf(o[j][dt][0]); pk.y = f2bf(o[j][dt][1]);
      pk.z = f2bf(o[j][dt][2]); pk.w = f2bf(o[j][dt][3]);
      *(short4*)&OPc[((size_t)(n0w + j * 16 + lr) << 7) + dt * 16 + q * 4] = pk;
    }
}

// ---------------- kernel 3: merge partials + W_z projection + BN2d + residual ----
// grid (256 nt of 16 rows, 4 b); block 256 = 4 waves (wave = c-quarter).
__global__ __launch_bounds__(256) void proj_kernel(const float* __restrict__ x,
                                                   char* ws, float* __restrict__ out) {
  const int nt = blockIdx.x, b = blockIdx.y;
  const int t = threadIdx.x, wv = t >> 6, l = t & 63, lr = l & 15, q = l >> 4;
  __shared__ __attribute__((aligned(16))) short ys[16][136];
  const short* OP = (const short*)(ws + WS_OP);
  const float* LP = (const float*)(ws + WS_LP);
  const short* WZ = (const short*)(ws + WS_WZ);
  const float* wzs = (const float*)(ws + WS_WZS);
  const float* wzt = (const float*)(ws + WS_WZT);
  const int n0 = nt * 16;
  {
    int row = t >> 4, d8 = (t & 15) * 8;
    int n = n0 + row;
    float acc8[8] = {};
    float lsf = 0.f;
    #pragma unroll
    for (int mc = 0; mc < 4; ++mc) {
      int cb = mc * 4 + b;
      const short* p = OP + ((size_t)cb << 19) + ((size_t)n << 7) + d8;
      uint4 v = *(const uint4*)p;
      uint32_t uu[4] = {v.x, v.y, v.z, v.w};
      #pragma unroll
      for (int w = 0; w < 4; ++w) {
        union { uint32_t u; float f; } lo, hi;
        lo.u = uu[w] << 16; hi.u = uu[w] & 0xffff0000u;
        acc8[w * 2 + 0] += lo.f;
        acc8[w * 2 + 1] += hi.f;
      }
      lsf += LP[(cb << 12) + n];
    }
    float inv = 1.0f / lsf;
    short out8[8];
    #pragma unroll
    for (int j = 0; j < 8; ++j) out8[j] = f2bf(acc8[j] * inv);
    *(uint4*)&ys[row][d8] = *(uint4*)out8;
  }
  __syncthreads();
  bf16x8 a[4];
  #pragma unroll
  for (int kt = 0; kt < 4; ++kt) a[kt] = *(const bf16x8*)&ys[lr][kt * 32 + q * 8];
  f32x4 acc[4] = {};
  #pragma unroll
  for (int kt = 0; kt < 4; ++kt) {
    #pragma unroll
    for (int s = 0; s < 4; ++s) {
      const short* wp = WZ + (size_t)(wv * 64 + s * 16 + lr) * 128 + kt * 32 + q * 8;
      bf16x8 bf = *(const bf16x8*)wp;
      acc[s] = mfma16(a[kt], bf, acc[s]);
    }
  }
  #pragma unroll
  for (int s = 0; s < 4; ++s) {
    int c = wv * 64 + s * 16 + lr;
    float sc = wzs[c], sh = wzt[c];
    int nbase = n0 + q * 4;
    size_t base = ((size_t)(b * 256 + c) << 12) + nbase;
    float4 xv = *(const float4*)(x + base);
    float4 ov;
    ov.x = acc[s][0] * sc + sh + xv.x;
    ov.y = acc[s][1] * sc + sh + xv.y;
    ov.z = acc[s][2] * sc + sh + xv.z;
    ov.w = acc[s][3] * sc + sh + xv.w;
    *(float4*)(out + base) = ov;
  }
}

// ---------------- launcher ----------------
extern "C" void kernel_launch(void* const* d_in, const int* in_sizes, int n_in,
                              void* d_out, int out_size, void* d_ws, size_t ws_size,
                              hipStream_t stream) {
  const float* x       = (const float*)d_in[0];
  const float* theta_w = (const float*)d_in[1];
  const float* theta_b = (const float*)d_in[2];
  const float* tg      = (const float*)d_in[3];
  const float* tb      = (const float*)d_in[4];
  const float* tm      = (const float*)d_in[5];
  const float* tv      = (const float*)d_in[6];
  const float* phi_w   = (const float*)d_in[7];
  const float* phi_b   = (const float*)d_in[8];
  const float* pg      = (const float*)d_in[9];
  const float* pb      = (const float*)d_in[10];
  const float* pm      = (const float*)d_in[11];
  const float* pv      = (const float*)d_in[12];
  const float* g_w     = (const float*)d_in[13];
  const float* g_b     = (const float*)d_in[14];
  const float* wz_w    = (const float*)d_in[15];
  const float* wz_b    = (const float*)d_in[16];
  const float* bg      = (const float*)d_in[17];
  const float* bb      = (const float*)d_in[18];
  const float* bm      = (const float*)d_in[19];
  const float* bv      = (const float*)d_in[20];
  char* ws = (char*)d_ws;
  float* out = (float*)d_out;

  prep_kernel<<<384, 256, 0, stream>>>(theta_w, phi_w, g_w, wz_w,
                                       theta_b, tg, tb, tm, tv,
                                       phi_b, pg, pb, pm, pv,
                                       g_b, wz_b, bg, bb, bm, bv, ws);
  qkv_kernel<<<dim3(128, 4), 256, 0, stream>>>(x, ws);
  attn_kernel<<<512, 256, 0, stream>>>(ws);
  proj_kernel<<<dim3(256, 4), 256, 0, stream>>>(x, ws, out);
}